// Round 5
// baseline (190.359 us; speedup 1.0000x reference)
//
#include <hip/hip_runtime.h>

// A3TGCN collapses (TGCN hidden state is None -> zeros every period) to:
//   agg = D^-1/2 (A + I) D^-1/2 X            [N,12]  (GCN aggregation)
//   Z[n,p,k]  = sigmoid(agg[n,p]*az[k] + bz[k])      az = conv_w_z @ lin_w_z[:128]
//   Ht[n,p,k] = tanh   (agg[n,p]*ah[k] + bh[k])
//   h[n,k]    = sum_p softmax(att)[p] * (1-Z)*Ht
//   out       = elu(h) @ W_out + b_out        [N,12]
// R-branch (d_in[8..11]) provably unused: H_state==0 so R gates nothing.
// Dtypes: float32 tensors + int32 indices (verified R2-R4, absmax 7.6e-6).
//
// R4 -> R5: pipeline cut to memset + 2 kernels.
//  - deg computed by fire-and-forget f32 atomics inside k_fill (R2 counters
//    proved native global_atomic_add_f32: 32B/atomic write-through, no CAS);
//    k_deg pass deleted, k_fused does rsqrt(1+deg) on the fly.
//  - weight-fold runs as one extra block of k_fill (hidden under fill).
//  - k_fused tail: precise-div chains (~8-10 inst each) replaced with v_rcp;
//    matvec spread over 120 threads; LDS coeffs packed float2 (ds_read_b64);
//    32-bit gather offsets.

#define PP 12
#define HH 128
#define OO 12
#define CAP 96

__device__ __forceinline__ float fast_rcp(float x) { return __builtin_amdgcn_rcpf(x); }
__device__ __forceinline__ float fast_rsq(float x) { return __builtin_amdgcn_rsqf(x); }

// ---- weight folding (device fn, run by one spare block of the fill kernel) ----
__device__ __forceinline__ void precompute_body(
    int k,
    const float* __restrict__ cwz, const float* __restrict__ cbz,
    const float* __restrict__ Wz, const float* __restrict__ lbz,
    const float* __restrict__ cwh, const float* __restrict__ cbh,
    const float* __restrict__ Wh, const float* __restrict__ lbh,
    const float* __restrict__ att,
    float* __restrict__ az, float* __restrict__ bz,
    float* __restrict__ ah, float* __restrict__ bh,
    float* __restrict__ probs) {
    float sz = 0.f, tz = 0.f, sh = 0.f, th = 0.f;
    for (int h = 0; h < HH; ++h) {
        float wz = Wz[h * HH + k];   // lin_w_z is (256,128); only first 128 rows used
        float wh = Wh[h * HH + k];
        sz += cwz[h] * wz;
        tz += cbz[h] * wz;
        sh += cwh[h] * wh;
        th += cbh[h] * wh;
    }
    az[k] = sz;
    bz[k] = tz + lbz[k];
    ah[k] = sh;
    bh[k] = th + lbh[k];
    if (k == 0) {
        float m = -1e30f;
        for (int p = 0; p < PP; ++p) m = fmaxf(m, att[p]);
        float e[PP], ssum = 0.f;
        for (int p = 0; p < PP; ++p) { e[p] = __expf(att[p] - m); ssum += e[p]; }
        float inv = 1.0f / ssum;
        for (int p = 0; p < PP; ++p) probs[p] = e[p] * inv;
    }
}

// ---- bucket fill + deg atomics; last block folds weights ----
__global__ void k_fill(const int* __restrict__ srcv, const int* __restrict__ dstv,
                       const float* __restrict__ ew, int* __restrict__ cursor,
                       float* __restrict__ deg, int2* __restrict__ bucket, int e,
                       const float* cwz, const float* cbz, const float* Wz, const float* lbz,
                       const float* cwh, const float* cbh, const float* Wh, const float* lbh,
                       const float* att,
                       float* az, float* bz, float* ah, float* bh, float* probs) {
    if (blockIdx.x == gridDim.x - 1) {
        if (threadIdx.x < HH)
            precompute_body(threadIdx.x, cwz, cbz, Wz, lbz, cwh, cbh, Wh, lbh, att,
                            az, bz, ah, bh, probs);
        return;
    }
    int i = blockIdx.x * blockDim.x + threadIdx.x;
    if (i >= e) return;
    int d = dstv[i];
    float w = ew[i];
    int pos = atomicAdd(&cursor[d], 1);
    if (pos < CAP) bucket[(long)d * CAP + pos] = make_int2(srcv[i], __float_as_int(w));
    atomicAdd(&deg[d], w);   // return unused -> fire-and-forget global_atomic_add_f32
}

// ---- CSR fallback build (used only if ws too small for buckets) ----
__global__ void k_hist(const int* __restrict__ dstv, const float* __restrict__ ew,
                       int* __restrict__ count, float* __restrict__ deg, int e) {
    int i = blockIdx.x * blockDim.x + threadIdx.x;
    if (i < e) {
        atomicAdd(&count[dstv[i]], 1);
        atomicAdd(&deg[dstv[i]], ew[i]);
    }
}

__global__ void __launch_bounds__(256) k_scan(const int* __restrict__ count,
                                              int* __restrict__ rowptr,
                                              int* __restrict__ cursor, int n) {
    __shared__ int s_sum[256];
    int t = threadIdx.x;
    int chunk = (n + 255) / 256;
    int lo = t * chunk, hi = min(n, lo + chunk);
    int s = 0;
    for (int i = lo; i < hi; ++i) s += count[i];
    s_sum[t] = s;
    __syncthreads();
    for (int off = 1; off < 256; off <<= 1) {
        int v = (t >= off) ? s_sum[t - off] : 0;
        __syncthreads();
        s_sum[t] += v;
        __syncthreads();
    }
    int run = (t == 0) ? 0 : s_sum[t - 1];
    for (int i = lo; i < hi; ++i) {
        rowptr[i] = run;
        cursor[i] = run;
        run += count[i];
    }
}

__global__ void k_fill_csr(const int* __restrict__ srcv, const int* __restrict__ dstv,
                           const float* __restrict__ ew, int* __restrict__ cursor,
                           int2* __restrict__ csr, int e,
                           const float* cwz, const float* cbz, const float* Wz, const float* lbz,
                           const float* cwh, const float* cbh, const float* Wh, const float* lbh,
                           const float* att,
                           float* az, float* bz, float* ah, float* bh, float* probs) {
    if (blockIdx.x == gridDim.x - 1) {
        if (threadIdx.x < HH)
            precompute_body(threadIdx.x, cwz, cbz, Wz, lbz, cwh, cbh, Wh, lbh, att,
                            az, bz, ah, bh, probs);
        return;
    }
    int i = blockIdx.x * blockDim.x + threadIdx.x;
    if (i >= e) return;
    int d = dstv[i];
    int pos = atomicAdd(&cursor[d], 1);
    csr[pos] = make_int2(srcv[i], __float_as_int(ew[i]));
}

// ---- fused: gather (LDS float2 coeffs) + gates + attention + elu + matvec ----
// cap>0: bucket layout, len=min(count,cap), base=node*cap. cap==0: CSR layout.
__global__ void __launch_bounds__(HH) k_fused(
    const int* __restrict__ rowptr, const int* __restrict__ count, int cap,
    const int2* __restrict__ csr, const float* __restrict__ deg,
    const float* __restrict__ x,
    const float* __restrict__ az, const float* __restrict__ bz,
    const float* __restrict__ ah, const float* __restrict__ bh,
    const float* __restrict__ probs,
    const float* __restrict__ Wout, const float* __restrict__ bout,
    float* __restrict__ out, int n) {
    __shared__ float2 s_cs[128];               // {coeff, bitcast 32-bit x-offset}
    __shared__ float s_part[PP][10];           // gather partials, then matvec partials
    __shared__ float s_agg[PP], s_probs[PP], s_h[HH];
    int node = blockIdx.x;
    int t = threadIdx.x;
    float dv_n = fast_rsq(1.0f + deg[node]);   // +1 = self-loop weight
    long base = (cap > 0) ? (long)node * cap : rowptr[node];
    int len = count[node];
    if (cap > 0) len = min(len, cap);
    if (t < PP) s_probs[t] = probs[t];
    int p = t % PP, j = t / PP;                // 120 gather threads: 12 periods x 10 slots
    float acc_g = (t < PP) ? dv_n * dv_n * x[node * PP + t] : 0.f;  // self loop
    if (t >= 120) acc_g = 0.f;
    for (int ch = 0; ch < len; ch += 128) {
        int clen = min(128, len - ch);
        __syncthreads();                       // s_cs reuse barrier (uniform trips)
        if (t < clen) {
            int2 sw = csr[base + ch + t];      // coalesced, once per edge
            float c = __int_as_float(sw.y) * fast_rsq(1.0f + deg[sw.x]) * dv_n;
            s_cs[t] = make_float2(c, __int_as_float(sw.x * PP));
        }
        __syncthreads();
        if (t < 120)
            for (int i = j; i < clen; i += 10) {   // one ds_read_b64 per edge-iter
                float2 cs = s_cs[i];
                acc_g += cs.x * x[__float_as_int(cs.y) + p];
            }
    }
    if (t < 120) s_part[p][j] = acc_g;
    __syncthreads();
    if (t < PP) {
        float a = 0.f;
#pragma unroll
        for (int j2 = 0; j2 < 10; ++j2) a += s_part[t][j2];
        s_agg[t] = a;
    }
    __syncthreads();
    // pointwise tail (all 128 threads, k = t); divisions -> v_rcp
    float a_z = az[t], b_z = bz[t], a_h = ah[t], b_h = bh[t];
    float acc = 0.0f;
#pragma unroll
    for (int q = 0; q < PP; ++q) {
        float g = s_agg[q];
        float omz = fast_rcp(1.0f + __expf(g * a_z + b_z));   // 1 - sigmoid
        float y = g * a_h + b_h;
        y = fminf(fmaxf(y, -15.0f), 15.0f);
        float e2 = __expf(2.0f * y);
        float tnh = 1.0f - 2.0f * fast_rcp(e2 + 1.0f);        // tanh
        acc += s_probs[q] * omz * tnh;
    }
    s_h[t] = acc > 0.0f ? acc : expm1f(acc);   // elu, alpha=1
    __syncthreads();
    // output matvec across 120 threads: output p, 10-way split over j
    if (t < 120) {
        float s = 0.f;
        for (int j2 = j; j2 < HH; j2 += 10) s += s_h[j2] * Wout[j2 * OO + p];
        s_part[p][j] = s;
    }
    __syncthreads();
    if (t < OO) {
        float s = bout[t];
#pragma unroll
        for (int j2 = 0; j2 < 10; ++j2) s += s_part[t][j2];
        out[node * OO + t] = s;
    }
}

extern "C" void kernel_launch(void* const* d_in, const int* in_sizes, int n_in,
                              void* d_out, int out_size, void* d_ws, size_t ws_size,
                              hipStream_t stream) {
    const float* x    = (const float*)d_in[0];
    const int*   ei   = (const int*)d_in[1];
    const float* ew   = (const float*)d_in[2];
    const float* att  = (const float*)d_in[3];
    const float* cwz  = (const float*)d_in[4];
    const float* cbz  = (const float*)d_in[5];
    const float* Wz   = (const float*)d_in[6];
    const float* lbz  = (const float*)d_in[7];
    const float* cwh  = (const float*)d_in[12];
    const float* cbh  = (const float*)d_in[13];
    const float* Wh   = (const float*)d_in[14];
    const float* lbh  = (const float*)d_in[15];
    const float* Wout = (const float*)d_in[16];
    const float* bout = (const float*)d_in[17];
    float* out = (float*)d_out;

    const int E = in_sizes[2];
    const int N = in_sizes[0] / PP;
    const int* srcv = ei;
    const int* dstv = ei + E;

    char* wsb = (char*)d_ws;
    size_t bucket_bytes = (size_t)N * CAP * sizeof(int2);
    size_t bucket_need = bucket_bytes + (size_t)N * 8 + (4 * HH + PP + 64) * 4;

    if (ws_size >= bucket_need) {
        // --- bucket path: memset + 2 kernels ---
        int2*  bucket = (int2*)wsb;
        int*   cursor = (int*)(wsb + bucket_bytes);
        float* deg    = (float*)(cursor + N);   // adjacent -> single memset
        float* az     = deg + N;
        float* bz     = az + HH;
        float* ah     = bz + HH;
        float* bh     = ah + HH;
        float* probs  = bh + HH;

        hipMemsetAsync(cursor, 0, (size_t)N * 2 * sizeof(int), stream);
        k_fill<<<(E + 255) / 256 + 1, 256, 0, stream>>>(srcv, dstv, ew, cursor, deg, bucket, E,
            cwz, cbz, Wz, lbz, cwh, cbh, Wh, lbh, att, az, bz, ah, bh, probs);
        k_fused<<<N, HH, 0, stream>>>(nullptr, cursor, CAP, bucket, deg, x,
                                      az, bz, ah, bh, probs, Wout, bout, out, N);
    } else {
        // --- CSR fallback: memset + 4 kernels ---
        int2*  csr    = (int2*)wsb;
        int*   count  = (int*)(wsb + (size_t)E * sizeof(int2));
        float* deg    = (float*)(count + N);    // adjacent -> single memset
        int*   rowptr = (int*)(deg + N);
        int*   cursor = rowptr + N;
        float* az     = (float*)(cursor + N);
        float* bz     = az + HH;
        float* ah     = bz + HH;
        float* bh     = ah + HH;
        float* probs  = bh + HH;

        hipMemsetAsync(count, 0, (size_t)N * 2 * sizeof(int), stream);
        k_hist<<<(E + 255) / 256, 256, 0, stream>>>(dstv, ew, count, deg, E);
        k_scan<<<1, 256, 0, stream>>>(count, rowptr, cursor, N);
        k_fill_csr<<<(E + 255) / 256 + 1, 256, 0, stream>>>(srcv, dstv, ew, cursor, csr, E,
            cwz, cbz, Wz, lbz, cwh, cbh, Wh, lbh, att, az, bz, ah, bh, probs);
        k_fused<<<N, HH, 0, stream>>>(rowptr, count, 0, csr, deg, x,
                                      az, bz, ah, bh, probs, Wout, bout, out, N);
    }
}

// Round 6
// 165.048 us; speedup vs baseline: 1.1534x; 1.1534x over previous
//
#include <hip/hip_runtime.h>

// A3TGCN collapses (TGCN hidden state is None -> zeros every period) to:
//   agg = D^-1/2 (A + I) D^-1/2 X            [N,12]  (GCN aggregation)
//   Z[n,p,k]  = sigmoid(agg[n,p]*az[k] + bz[k])      az = conv_w_z @ lin_w_z[:128]
//   Ht[n,p,k] = tanh   (agg[n,p]*ah[k] + bh[k])
//   h[n,k]    = sum_p softmax(att)[p] * (1-Z)*Ht
//   out       = elu(h) @ W_out + b_out        [N,12]
// R-branch (d_in[8..11]) provably unused: H_state==0 so R gates nothing.
// Dtypes: float32 tensors + int32 indices (verified R2-R5, absmax 7.6e-6).
//
// R5 -> R6: fill was at the ~19 atomics/ns device wall with 2 atomics/edge
// (1.28M/72us). Back to 1 atomic/edge (cursor only); deg via atomic-free
// wave-per-node k_prep, which also pre-scales y = dinv*x so the hot gather
// needs no deg[src] fetch. k_fused rewritten wave-per-node, barrier-free:
// register+shfl staging, 12x4 gather layout with shfl_xor reduce, 2 k's per
// lane in the gate tail, butterfly-reduced output matvec.

#define PP 12
#define HH 128
#define OO 12
#define CAP 96

__device__ __forceinline__ float fast_rcp(float x) { return __builtin_amdgcn_rcpf(x); }
__device__ __forceinline__ float fast_rsq(float x) { return __builtin_amdgcn_rsqf(x); }

// ---- weight folding (device fn, run by one spare block of the fill kernel) ----
__device__ __forceinline__ void precompute_body(
    int k,
    const float* __restrict__ cwz, const float* __restrict__ cbz,
    const float* __restrict__ Wz, const float* __restrict__ lbz,
    const float* __restrict__ cwh, const float* __restrict__ cbh,
    const float* __restrict__ Wh, const float* __restrict__ lbh,
    const float* __restrict__ att,
    float* __restrict__ az, float* __restrict__ bz,
    float* __restrict__ ah, float* __restrict__ bh,
    float* __restrict__ probs) {
    float sz = 0.f, tz = 0.f, sh = 0.f, th = 0.f;
    for (int h = 0; h < HH; ++h) {
        float wz = Wz[h * HH + k];   // lin_w_z is (256,128); only first 128 rows used
        float wh = Wh[h * HH + k];
        sz += cwz[h] * wz;
        tz += cbz[h] * wz;
        sh += cwh[h] * wh;
        th += cbh[h] * wh;
    }
    az[k] = sz;
    bz[k] = tz + lbz[k];
    ah[k] = sh;
    bh[k] = th + lbh[k];
    if (k == 0) {
        float m = -1e30f;
        for (int p = 0; p < PP; ++p) m = fmaxf(m, att[p]);
        float e[PP], ssum = 0.f;
        for (int p = 0; p < PP; ++p) { e[p] = __expf(att[p] - m); ssum += e[p]; }
        float inv = 1.0f / ssum;
        for (int p = 0; p < PP; ++p) probs[p] = e[p] * inv;
    }
}

// ---- bucket fill (1 atomic/edge); last block folds weights ----
__global__ void k_fill(const int* __restrict__ srcv, const int* __restrict__ dstv,
                       const float* __restrict__ ew, int* __restrict__ cursor,
                       int2* __restrict__ bucket, int e,
                       const float* cwz, const float* cbz, const float* Wz, const float* lbz,
                       const float* cwh, const float* cbh, const float* Wh, const float* lbh,
                       const float* att,
                       float* az, float* bz, float* ah, float* bh, float* probs) {
    if (blockIdx.x == gridDim.x - 1) {
        if (threadIdx.x < HH)
            precompute_body(threadIdx.x, cwz, cbz, Wz, lbz, cwh, cbh, Wh, lbh, att,
                            az, bz, ah, bh, probs);
        return;
    }
    int i = blockIdx.x * blockDim.x + threadIdx.x;
    if (i >= e) return;
    int d = dstv[i];
    int pos = atomicAdd(&cursor[d], 1);
    if (pos < CAP) bucket[(long)d * CAP + pos] = make_int2(srcv[i], __float_as_int(ew[i]));
}

// ---- CSR fallback build ----
__global__ void k_hist(const int* __restrict__ dstv, int* __restrict__ count, int e) {
    int i = blockIdx.x * blockDim.x + threadIdx.x;
    if (i < e) atomicAdd(&count[dstv[i]], 1);
}

__global__ void __launch_bounds__(256) k_scan(const int* __restrict__ count,
                                              int* __restrict__ rowptr,
                                              int* __restrict__ cursor, int n) {
    __shared__ int s_sum[256];
    int t = threadIdx.x;
    int chunk = (n + 255) / 256;
    int lo = t * chunk, hi = min(n, lo + chunk);
    int s = 0;
    for (int i = lo; i < hi; ++i) s += count[i];
    s_sum[t] = s;
    __syncthreads();
    for (int off = 1; off < 256; off <<= 1) {
        int v = (t >= off) ? s_sum[t - off] : 0;
        __syncthreads();
        s_sum[t] += v;
        __syncthreads();
    }
    int run = (t == 0) ? 0 : s_sum[t - 1];
    for (int i = lo; i < hi; ++i) {
        rowptr[i] = run;
        cursor[i] = run;
        run += count[i];
    }
}

__global__ void k_fill_csr(const int* __restrict__ srcv, const int* __restrict__ dstv,
                           const float* __restrict__ ew, int* __restrict__ cursor,
                           int2* __restrict__ csr, int e,
                           const float* cwz, const float* cbz, const float* Wz, const float* lbz,
                           const float* cwh, const float* cbh, const float* Wh, const float* lbh,
                           const float* att,
                           float* az, float* bz, float* ah, float* bh, float* probs) {
    if (blockIdx.x == gridDim.x - 1) {
        if (threadIdx.x < HH)
            precompute_body(threadIdx.x, cwz, cbz, Wz, lbz, cwh, cbh, Wh, lbh, att,
                            az, bz, ah, bh, probs);
        return;
    }
    int i = blockIdx.x * blockDim.x + threadIdx.x;
    if (i >= e) return;
    int d = dstv[i];
    int pos = atomicAdd(&cursor[d], 1);
    csr[pos] = make_int2(srcv[i], __float_as_int(ew[i]));
}

// ---- wave-per-node: deg -> dinv, y = dinv * x (atomic-free) ----
// cap>0: bucket layout (base=node*cap, len=min(count,cap)); cap==0: CSR.
__global__ void __launch_bounds__(256) k_prep(
    const int* __restrict__ rowptr, const int* __restrict__ count, int cap,
    const int2* __restrict__ bucket, const float* __restrict__ x,
    float* __restrict__ dinv, float* __restrict__ y, int n) {
    int wid = (blockIdx.x * blockDim.x + threadIdx.x) >> 6;
    int lane = threadIdx.x & 63;
    if (wid >= n) return;
    long base = (cap > 0) ? (long)wid * cap : rowptr[wid];
    int len = count[wid];
    if (cap > 0) len = min(len, cap);
    float s = 0.f;
    for (int i = lane; i < len; i += 64) s += __int_as_float(bucket[base + i].y);
#pragma unroll
    for (int off = 32; off > 0; off >>= 1) s += __shfl_xor(s, off, 64);
    float dv = fast_rsq(1.0f + s);             // +1 = self-loop weight
    if (lane == 0) dinv[wid] = dv;
    if (lane < PP) y[wid * PP + lane] = dv * x[wid * PP + lane];
}

// ---- wave-per-node fused: gather y + gates + attention + elu + matvec ----
// Barrier-free: register staging + shfl. agg = dinv_n * (sum w*y[src] + y[node]).
__global__ void __launch_bounds__(256) k_fused(
    const int* __restrict__ rowptr, const int* __restrict__ count, int cap,
    const int2* __restrict__ bucket, const float* __restrict__ dinv,
    const float* __restrict__ y,
    const float* __restrict__ az, const float* __restrict__ bz,
    const float* __restrict__ ah, const float* __restrict__ bh,
    const float* __restrict__ probs,
    const float* __restrict__ Wout, const float* __restrict__ bout,
    float* __restrict__ out, int n) {
    int node = (blockIdx.x * blockDim.x + threadIdx.x) >> 6;
    int lane = threadIdx.x & 63;
    if (node >= n) return;                      // node uniform per wave: safe with shfl
    long base = (cap > 0) ? (long)node * cap : rowptr[node];
    int len = count[node];
    if (cap > 0) len = min(len, cap);
    float dv_n = dinv[node];
    int j = lane & 3, pg = lane >> 2;           // 12 p-groups x 4 slots (lanes 0-47 gather)
    float acc = 0.f;
    if (lane < 48 && j == 0) acc = y[node * PP + pg];   // self-loop term
    for (int ch = 0; ch < len; ch += 64) {
        int idx = ch + lane;
        int2 sw = make_int2(0, 0);
        if (idx < len) sw = bucket[base + idx];         // coalesced, one edge per lane
        float w = __int_as_float(sw.y);
        int off = sw.x * PP;
        int clen = min(64, len - ch);
        for (int s = j; s < clen; s += 4) {             // broadcast via shfl, no LDS
            float ww = __shfl(w, s, 64);
            int oo = __shfl(off, s, 64);
            if (lane < 48) acc += ww * y[oo + pg];
        }
    }
    acc += __shfl_xor(acc, 1, 64);
    acc += __shfl_xor(acc, 2, 64);              // lanes 4p..4p+3 now hold sum for period p
    // gate tail: two k's per lane (k0=lane, k1=lane+64)
    float az0 = az[lane], bz0 = bz[lane], ah0 = ah[lane], bh0 = bh[lane];
    float az1 = az[lane + 64], bz1 = bz[lane + 64], ah1 = ah[lane + 64], bh1 = bh[lane + 64];
    float h0 = 0.f, h1 = 0.f;
#pragma unroll
    for (int p = 0; p < PP; ++p) {
        float g = dv_n * __shfl(acc, 4 * p, 64);
        float pr = probs[p];
        float o0 = fast_rcp(1.f + __expf(fmaf(g, az0, bz0)));        // 1 - sigmoid
        float v0 = fminf(fmaxf(fmaf(g, ah0, bh0), -15.f), 15.f);
        float t0 = 1.f - 2.f * fast_rcp(__expf(2.f * v0) + 1.f);     // tanh
        h0 = fmaf(pr * o0, t0, h0);
        float o1 = fast_rcp(1.f + __expf(fmaf(g, az1, bz1)));
        float v1 = fminf(fmaxf(fmaf(g, ah1, bh1), -15.f), 15.f);
        float t1 = 1.f - 2.f * fast_rcp(__expf(2.f * v1) + 1.f);
        h1 = fmaf(pr * o1, t1, h1);
    }
    h0 = h0 > 0.f ? h0 : __expf(h0) - 1.f;      // elu (exp-1: |abs err| ~1e-7, ok)
    h1 = h1 > 0.f ? h1 : __expf(h1) - 1.f;
    // output matvec: per-lane partials for all 12 outputs, butterfly reduce
    float part[OO];
#pragma unroll
    for (int q = 0; q < OO; ++q)
        part[q] = fmaf(h0, Wout[lane * OO + q], h1 * Wout[(lane + 64) * OO + q]);
#pragma unroll
    for (int off2 = 32; off2 > 0; off2 >>= 1) {
#pragma unroll
        for (int q = 0; q < OO; ++q) part[q] += __shfl_xor(part[q], off2, 64);
    }
    if (lane == 0) {
#pragma unroll
        for (int q = 0; q < OO; ++q) out[node * OO + q] = part[q] + bout[q];
    }
}

extern "C" void kernel_launch(void* const* d_in, const int* in_sizes, int n_in,
                              void* d_out, int out_size, void* d_ws, size_t ws_size,
                              hipStream_t stream) {
    const float* x    = (const float*)d_in[0];
    const int*   ei   = (const int*)d_in[1];
    const float* ew   = (const float*)d_in[2];
    const float* att  = (const float*)d_in[3];
    const float* cwz  = (const float*)d_in[4];
    const float* cbz  = (const float*)d_in[5];
    const float* Wz   = (const float*)d_in[6];
    const float* lbz  = (const float*)d_in[7];
    const float* cwh  = (const float*)d_in[12];
    const float* cbh  = (const float*)d_in[13];
    const float* Wh   = (const float*)d_in[14];
    const float* lbh  = (const float*)d_in[15];
    const float* Wout = (const float*)d_in[16];
    const float* bout = (const float*)d_in[17];
    float* out = (float*)d_out;

    const int E = in_sizes[2];
    const int N = in_sizes[0] / PP;
    const int* srcv = ei;
    const int* dstv = ei + E;

    char* wsb = (char*)d_ws;
    size_t bucket_bytes = (size_t)N * CAP * sizeof(int2);
    size_t tail_bytes = (size_t)N * (1 + 1 + PP) * 4 + (4 * HH + PP + 64) * 4;
    size_t bucket_need = bucket_bytes + tail_bytes;

    if (ws_size >= bucket_need) {
        // --- bucket path: memset + 3 kernels ---
        int2*  bucket = (int2*)wsb;
        int*   cursor = (int*)(wsb + bucket_bytes);
        float* dinv   = (float*)(cursor + N);
        float* y      = dinv + N;
        float* az     = y + (size_t)N * PP;
        float* bz     = az + HH;
        float* ah     = bz + HH;
        float* bh     = ah + HH;
        float* probs  = bh + HH;

        hipMemsetAsync(cursor, 0, (size_t)N * sizeof(int), stream);
        k_fill<<<(E + 255) / 256 + 1, 256, 0, stream>>>(srcv, dstv, ew, cursor, bucket, E,
            cwz, cbz, Wz, lbz, cwh, cbh, Wh, lbh, att, az, bz, ah, bh, probs);
        k_prep<<<((long)N * 64 + 255) / 256, 256, 0, stream>>>(
            nullptr, cursor, CAP, bucket, x, dinv, y, N);
        k_fused<<<((long)N * 64 + 255) / 256, 256, 0, stream>>>(
            nullptr, cursor, CAP, bucket, dinv, y,
            az, bz, ah, bh, probs, Wout, bout, out, N);
    } else {
        // --- CSR fallback: memset + 5 kernels ---
        int2*  csr    = (int2*)wsb;
        int*   count  = (int*)(wsb + (size_t)E * sizeof(int2));
        int*   rowptr = count + N;
        int*   cursor = rowptr + N;
        float* dinv   = (float*)(cursor + N);
        float* y      = dinv + N;
        float* az     = y + (size_t)N * PP;
        float* bz     = az + HH;
        float* ah     = bz + HH;
        float* bh     = ah + HH;
        float* probs  = bh + HH;

        hipMemsetAsync(count, 0, (size_t)N * sizeof(int), stream);
        k_hist<<<(E + 255) / 256, 256, 0, stream>>>(dstv, count, E);
        k_scan<<<1, 256, 0, stream>>>(count, rowptr, cursor, N);
        k_fill_csr<<<(E + 255) / 256 + 1, 256, 0, stream>>>(srcv, dstv, ew, cursor, csr, E,
            cwz, cbz, Wz, lbz, cwh, cbh, Wh, lbh, att, az, bz, ah, bh, probs);
        k_prep<<<((long)N * 64 + 255) / 256, 256, 0, stream>>>(
            rowptr, count, 0, csr, x, dinv, y, N);
        k_fused<<<((long)N * 64 + 255) / 256, 256, 0, stream>>>(
            rowptr, count, 0, csr, dinv, y,
            az, bz, ah, bh, probs, Wout, bout, out, N);
    }
}